// Round 1
// 854.788 us; speedup vs baseline: 2.1110x; 2.1110x over previous
//
#include <hip/hip_runtime.h>
#include <math.h>

#define BATCH 1024
#define CDIM 256
#define NHEADS 8
#define NTOK 64
#define SCALE 0.17677669529663687f  // 32^-0.5

typedef _Float16 h8 __attribute__((ext_vector_type(8)));
typedef _Float16 h2 __attribute__((ext_vector_type(2)));
typedef float f4 __attribute__((ext_vector_type(4)));

#define MFMA16(a, b, c) __builtin_amdgcn_mfma_f32_16x16x32_f16((a), (b), (c), 0, 0, 0)

// ---- pre-split W in workspace: [2 planes][1024 rows][256 ch][(wr,-wi)] halves
#define WSPLANE 524288        // halves per plane = 1024 * 512
// ---- mid in workspace: per batch [2 planes][256 ch][64 tok] h2 = 65536 halves
#define MID_BATCH 65536
#define MID_LO    32768

// ---- attn LDS plane offsets (halves) ----
// Phase 1 staging:
#define WAH_O 0        // [96][72] hi of (wr, -wi)
#define WAL_O 6912     // [96][72] lo
#define XCH_O 13824    // [64][72] hi of (xr, xi)
#define XCL_O 18432    // [64][72] lo                -> ends 23040
// Phase 2+ aliases the dead staging region (barrier-separated):
#define KAH_O 0        // [64][72] hi of (kr, ki)
#define KAL_O 4608     // [64][72] lo
#define VA_O  9216     // [32][136] (vr, -vi) rows = d, cols = 2*tok
#define PC_O  13568    // [64][136] (pr, pi)  rows = query, cols = 2*key  -> ends 22272
#define A_LDS_HALFS 23040   // 46080 B -> 3 blocks/CU (was 62976 B -> 2)

// ---- proj LDS (halves) ----
#define PWAH_O 0       // [64][72] hi of (wr, -wi)
#define PWAL_O 4608
#define PXCH_O 9216    // [64][72] hi of (or, oi)
#define PXCL_O 13824
#define P_LDS_HALFS 18432   // 36864 B -> 4 blocks/CU

#define PLANE 16777216LL

// split v into f16 hi + f16 lo (residual ~2^-22 relative)
__device__ __forceinline__ void fsplit(float v, _Float16& hi, _Float16& lo) {
    _Float16 h = (_Float16)v;
    hi = h;
    lo = (_Float16)(v - (float)h);
}

// (a,b) per word -> swap halves, negate new LOW half: (p,-q) -> (q,p)
__device__ __forceinline__ h8 rot_neg_lo(h8 a) {
    union { h8 h; unsigned int w[4]; } u; u.h = a;
#pragma unroll
    for (int i = 0; i < 4; i++) {
        unsigned int t = u.w[i];
        t = (t >> 16) | (t << 16);
        u.w[i] = t ^ 0x00008000u;
    }
    return u.h;
}
// (p,q) -> (q,-p)
__device__ __forceinline__ h8 rot_neg_hi(h8 a) {
    union { h8 h; unsigned int w[4]; } u; u.h = a;
#pragma unroll
    for (int i = 0; i < 4; i++) {
        unsigned int t = u.w[i];
        t = (t >> 16) | (t << 16);
        u.w[i] = t ^ 0x80000000u;
    }
    return u.h;
}

// ---------------------------------------------------------------------------
// One-time W pre-split: rows 0..767 = w_qkv, rows 768..1023 = w_proj.
// Stores interleaved (hi(wr), hi(-wi)) in plane 0, (lo(wr), lo(-wi)) in plane 1.
// ---------------------------------------------------------------------------
__global__ __launch_bounds__(256) void wsplit_kernel(
    const float* __restrict__ wqr, const float* __restrict__ wqi,
    const float* __restrict__ wpr, const float* __restrict__ wpi,
    _Float16* __restrict__ wsp)
{
    int g = blockIdx.x * 256 + threadIdx.x;   // 0..65535
    int row = g >> 6;                          // 0..1023 (wave-uniform)
    int c = (g & 63) * 4;
    const float* wrp; const float* wip; int srow;
    if (row < 768) { wrp = wqr; wip = wqi; srow = row; }
    else           { wrp = wpr; wip = wpi; srow = row - 768; }
    float4 r4 = *(const float4*)&wrp[srow * 256 + c];
    float4 i4 = *(const float4*)&wip[srow * 256 + c];
    const float* rp = &r4.x;
    const float* ip = &i4.x;
    h8 hi, lo;
#pragma unroll
    for (int j = 0; j < 4; j++) {
        _Float16 h0, l0, h1, l1;
        fsplit(rp[j], h0, l0);
        fsplit(-ip[j], h1, l1);
        hi[2 * j] = h0; hi[2 * j + 1] = h1;
        lo[2 * j] = l0; lo[2 * j + 1] = l1;
    }
    *(h8*)&wsp[(size_t)row * 512 + 2 * c] = hi;
    *(h8*)&wsp[WSPLANE + (size_t)row * 512 + 2 * c] = lo;
}

// ---------------------------------------------------------------------------
// MFMA attention kernel: one block per (local-batch, head), 256 thr = 4 waves.
// W pre-split in global; Q kept in registers (no LDS round-trip); output mid
// stored pre-split (hi/lo) for the proj MFMA kernel.
// ---------------------------------------------------------------------------
__global__ __launch_bounds__(256) void attn_kernel(
    const float* __restrict__ xr, const float* __restrict__ xi,
    const _Float16* __restrict__ wsp,
    const float* __restrict__ bias_table, const int* __restrict__ rel_index,
    _Float16* __restrict__ mid, int b0)
{
    const int blk = blockIdx.x;
    // XCD swizzle: put all 8 head-blocks of a batch on the same XCD (blk%8).
    int bl, h;
    if ((gridDim.x & 63) == 0) {           // nb multiple of 8
        int xcd = blk & 7;
        int slot = blk >> 3;
        h  = slot & 7;
        bl = ((slot >> 3) << 3) | xcd;
    } else { bl = blk >> 3; h = blk & 7; }
    const int b  = b0 + bl;
    const int t  = threadIdx.x;
    const int ln   = t & 15;         // frag 16-index
    const int quad = (t >> 4) & 3;   // frag k-quad
    const int wv   = t >> 6;         // wave id = token-group

    __shared__ alignas(16) _Float16 lds[A_LDS_HALFS];

    // ---- Phase 1: QKV projection. acc tiles: mt 0,1=q 2,3=k 4,5=v
    f4 accR[6], accI[6];
#pragma unroll
    for (int m = 0; m < 6; m++) {
        accR[m] = (f4){0.f, 0.f, 0.f, 0.f};
        accI[m] = (f4){0.f, 0.f, 0.f, 0.f};
    }

    for (int chunk = 0; chunk < 8; chunk++) {   // 32 channels per chunk
        __syncthreads();
        // stage W: pre-split copy, 96 rows x 32 ch
#pragma unroll
        for (int i = 0; i < 3; i++) {
            int p = t + i * 256;               // < 768
            int row = p >> 3, c4 = p & 7;
            int grow = (row < 32) ? (h * 32 + row)
                     : (row < 64) ? (256 + h * 32 + (row - 32))
                                  : (512 + h * 32 + (row - 64));
            const _Float16* wp = &wsp[(size_t)grow * 512 + chunk * 64 + c4 * 8];
            h8 hi = *(const h8*)wp;
            h8 lo = *(const h8*)(wp + WSPLANE);
            *(h8*)&lds[WAH_O + row * 72 + 8 * c4] = hi;
            *(h8*)&lds[WAL_O + row * 72 + 8 * c4] = lo;
        }
        // stage X transposed: [tok][(xr,xi) pairs], split in-kernel
#pragma unroll
        for (int i = 0; i < 2; i++) {
            int p = t + i * 256;               // < 512
            int tok = p & 63, c4g = p >> 6;    // c4g 0..7
            int c = chunk * 32 + c4g * 4;
            h8 hi, lo;
#pragma unroll
            for (int j = 0; j < 4; j++) {
                float xrv = xr[(b * 256 + c + j) * 64 + tok];
                float xiv = xi[(b * 256 + c + j) * 64 + tok];
                _Float16 h0, l0, h1, l1;
                fsplit(xrv, h0, l0);
                fsplit(xiv, h1, l1);
                hi[2 * j] = h0; hi[2 * j + 1] = h1;
                lo[2 * j] = l0; lo[2 * j + 1] = l1;
            }
            *(h8*)&lds[XCH_O + tok * 72 + 8 * c4g] = hi;
            *(h8*)&lds[XCL_O + tok * 72 + 8 * c4g] = lo;
        }
        __syncthreads();
#pragma unroll
        for (int ks = 0; ks < 2; ks++) {
            h8 bxh = *(const h8*)&lds[XCH_O + (wv * 16 + ln) * 72 + ks * 32 + quad * 8];
            h8 bxl = *(const h8*)&lds[XCL_O + (wv * 16 + ln) * 72 + ks * 32 + quad * 8];
#pragma unroll
            for (int mt = 0; mt < 6; mt++) {
                h8 wah = *(const h8*)&lds[WAH_O + (mt * 16 + ln) * 72 + ks * 32 + quad * 8];
                h8 wal = *(const h8*)&lds[WAL_O + (mt * 16 + ln) * 72 + ks * 32 + quad * 8];
                h8 wbh = rot_neg_lo(wah);
                h8 wbl = rot_neg_lo(wal);
                accR[mt] = MFMA16(wah, bxh, accR[mt]);
                accR[mt] = MFMA16(wah, bxl, accR[mt]);
                accR[mt] = MFMA16(wal, bxh, accR[mt]);
                accI[mt] = MFMA16(wbh, bxh, accI[mt]);
                accI[mt] = MFMA16(wbh, bxl, accI[mt]);
                accI[mt] = MFMA16(wbl, bxh, accI[mt]);
            }
        }
    }
    __syncthreads();

    // ---- Phase 2: scatter k (split hi/lo) and v (single f16) to LDS.
    // Q stays in registers: phase-3's Q read was an exact same-lane round trip.
    {
        const int tok = wv * 16 + ln;
#pragma unroll
        for (int mt = 2; mt < 4; mt++) {
            int d0 = (mt - 2) * 16 + quad * 4;
            h8 hi, lo;
#pragma unroll
            for (int r = 0; r < 4; r++) {
                _Float16 h0, l0, h1, l1;
                fsplit(accR[mt][r], h0, l0);
                fsplit(accI[mt][r], h1, l1);
                hi[2 * r] = h0; hi[2 * r + 1] = h1;
                lo[2 * r] = l0; lo[2 * r + 1] = l1;
            }
            *(h8*)&lds[KAH_O + tok * 72 + 2 * d0] = hi;
            *(h8*)&lds[KAL_O + tok * 72 + 2 * d0] = lo;
        }
#pragma unroll
        for (int mt = 4; mt < 6; mt++) {
#pragma unroll
            for (int r = 0; r < 4; r++) {
                int d = (mt - 4) * 16 + quad * 4 + r;
                h2 va = {(_Float16)accR[mt][r], (_Float16)(-accI[mt][r])};
                *(h2*)&lds[VA_O + d * 136 + 2 * tok] = va;
            }
        }
    }
    __syncthreads();

    // ---- Phase 3: S = scale*(Q conj(K)^H) + bias; magnitude softmax; P -> LDS
    {
        f4 sR[4], sI[4];
#pragma unroll
        for (int m = 0; m < 4; m++) {
            sR[m] = (f4){0.f, 0.f, 0.f, 0.f};
            sI[m] = (f4){0.f, 0.f, 0.f, 0.f};
        }
#pragma unroll
        for (int ks = 0; ks < 2; ks++) {
            // Q fragment built in-register from phase-1 acc (mt = ks)
            h8 qh, ql;
#pragma unroll
            for (int r = 0; r < 4; r++) {
                _Float16 h0, l0, h1, l1;
                fsplit(accR[ks][r], h0, l0);
                fsplit(accI[ks][r], h1, l1);
                qh[2 * r] = h0; qh[2 * r + 1] = h1;
                ql[2 * r] = l0; ql[2 * r + 1] = l1;
            }
            h8 qbh = rot_neg_hi(qh);   // (qi, -qr)
            h8 qbl = rot_neg_hi(ql);
#pragma unroll
            for (int mt = 0; mt < 4; mt++) {
                h8 kh = *(const h8*)&lds[KAH_O + (mt * 16 + ln) * 72 + ks * 32 + quad * 8];
                h8 kl = *(const h8*)&lds[KAL_O + (mt * 16 + ln) * 72 + ks * 32 + quad * 8];
                sR[mt] = MFMA16(qh, kh, sR[mt]);
                sR[mt] = MFMA16(qh, kl, sR[mt]);
                sR[mt] = MFMA16(ql, kh, sR[mt]);
                sI[mt] = MFMA16(qbh, kh, sI[mt]);
                sI[mt] = MFMA16(qbh, kl, sI[mt]);
                sI[mt] = MFMA16(qbl, kh, sI[mt]);
            }
        }
#pragma unroll
        for (int r = 0; r < 4; r++) {
            int qrow = wv * 16 + quad * 4 + r;
            float pr[4], pi[4], mg[4], e[4];
            float mx = -1e30f;
#pragma unroll
            for (int mt = 0; mt < 4; mt++) {
                int mcol = mt * 16 + ln;
                float bias = bias_table[rel_index[qrow * 64 + mcol] * 8 + h];
                float srv = sR[mt][r] * SCALE + bias;
                float siv = sI[mt][r] * SCALE;
                pr[mt] = srv; pi[mt] = siv;
                mg[mt] = sqrtf(srv * srv + siv * siv);
                mx = fmaxf(mx, mg[mt]);
            }
            mx = fmaxf(mx, __shfl_xor(mx, 1));
            mx = fmaxf(mx, __shfl_xor(mx, 2));
            mx = fmaxf(mx, __shfl_xor(mx, 4));
            mx = fmaxf(mx, __shfl_xor(mx, 8));
            float se = 0.f;
#pragma unroll
            for (int mt = 0; mt < 4; mt++) { e[mt] = expf(mg[mt] - mx); se += e[mt]; }
            se += __shfl_xor(se, 1);
            se += __shfl_xor(se, 2);
            se += __shfl_xor(se, 4);
            se += __shfl_xor(se, 8);
            float inv = 1.0f / se;
#pragma unroll
            for (int mt = 0; mt < 4; mt++) {
                float f = e[mt] * inv / (mg[mt] + 1e-8f);
                h2 p = {(_Float16)(pr[mt] * f), (_Float16)(pi[mt] * f)};
                *(h2*)&lds[PC_O + qrow * 136 + 2 * (mt * 16 + ln)] = p;
            }
        }
    }
    __syncthreads();

    // ---- Phase 4: O = P V (complex); store mid pre-split (hi/lo planes)
    {
        f4 oR[2], oI[2];
#pragma unroll
        for (int m = 0; m < 2; m++) {
            oR[m] = (f4){0.f, 0.f, 0.f, 0.f};
            oI[m] = (f4){0.f, 0.f, 0.f, 0.f};
        }
#pragma unroll
        for (int ks = 0; ks < 4; ks++) {
            h8 ap = *(const h8*)&lds[PC_O + (wv * 16 + ln) * 136 + ks * 32 + quad * 8];
#pragma unroll
            for (int dt = 0; dt < 2; dt++) {
                h8 va = *(const h8*)&lds[VA_O + (dt * 16 + ln) * 136 + ks * 32 + quad * 8];
                h8 vb = rot_neg_lo(va);    // (vi, vr)
                oR[dt] = MFMA16(ap, va, oR[dt]);
                oI[dt] = MFMA16(ap, vb, oI[dt]);
            }
        }
        _Float16* mB = mid + (size_t)bl * MID_BATCH;
#pragma unroll
        for (int dt = 0; dt < 2; dt++) {
            int c = h * 32 + dt * 16 + ln;
            int tbase = wv * 16 + quad * 4;
            h8 hv, lv;
#pragma unroll
            for (int r = 0; r < 4; r++) {
                _Float16 hr, lr, hx, lx;
                fsplit(oR[dt][r], hr, lr);
                fsplit(oI[dt][r], hx, lx);
                hv[2 * r] = hr; hv[2 * r + 1] = hx;
                lv[2 * r] = lr; lv[2 * r + 1] = lx;
            }
            *(h8*)&mB[(size_t)(c * 64 + tbase) * 2] = hv;
            *(h8*)&mB[MID_LO + (size_t)(c * 64 + tbase) * 2] = lv;
        }
    }
}

// ---------------------------------------------------------------------------
// Proj kernel, MFMA split-f16: one block per (local-batch, out-quarter).
// Same structure as attn phase 1; W pre-split, mid pre-split -> staging is copy.
// ---------------------------------------------------------------------------
__global__ __launch_bounds__(256) void proj_kernel(
    const _Float16* __restrict__ wsp,
    const _Float16* __restrict__ mid,
    float* __restrict__ out, int b0, long long out_floats)
{
    const int blk = blockIdx.x;
    // XCD swizzle: 4 quarter-blocks of a batch on one XCD
    int bl, qtr;
    if ((gridDim.x & 31) == 0) {           // nb multiple of 8
        int xcd = blk & 7;
        int slot = blk >> 3;
        qtr = slot & 3;
        bl  = ((slot >> 2) << 3) | xcd;
    } else { bl = blk >> 2; qtr = blk & 3; }
    const int b  = b0 + bl;
    const int t  = threadIdx.x;
    const int ln   = t & 15;
    const int quad = (t >> 4) & 3;
    const int wv   = t >> 6;

    __shared__ alignas(16) _Float16 lds[P_LDS_HALFS];
    const _Float16* mB = mid + (size_t)bl * MID_BATCH;

    f4 accR[4], accI[4];
#pragma unroll
    for (int m = 0; m < 4; m++) {
        accR[m] = (f4){0.f, 0.f, 0.f, 0.f};
        accI[m] = (f4){0.f, 0.f, 0.f, 0.f};
    }

    for (int chunk = 0; chunk < 8; chunk++) {
        __syncthreads();
        // stage W_proj: 64 rows x 32 ch, pre-split copy
#pragma unroll
        for (int i = 0; i < 2; i++) {
            int p = t + i * 256;               // < 512
            int row = p >> 3, c4 = p & 7;
            int grow = 768 + qtr * 64 + row;
            const _Float16* wp = &wsp[(size_t)grow * 512 + chunk * 64 + c4 * 8];
            h8 hi = *(const h8*)wp;
            h8 lo = *(const h8*)(wp + WSPLANE);
            *(h8*)&lds[PWAH_O + row * 72 + 8 * c4] = hi;
            *(h8*)&lds[PWAL_O + row * 72 + 8 * c4] = lo;
        }
        // stage O (mid) transposed: [tok][(or,oi) pairs], pure h2 copies
#pragma unroll
        for (int i = 0; i < 2; i++) {
            int p = t + i * 256;               // < 512
            int tok = p & 63, c4g = p >> 6;
            int c = chunk * 32 + c4g * 4;
            h8 hi, lo;
#pragma unroll
            for (int j = 0; j < 4; j++) {
                h2 hv = *(const h2*)&mB[(size_t)((c + j) * 64 + tok) * 2];
                h2 lv = *(const h2*)&mB[MID_LO + (size_t)((c + j) * 64 + tok) * 2];
                hi[2 * j] = hv[0]; hi[2 * j + 1] = hv[1];
                lo[2 * j] = lv[0]; lo[2 * j + 1] = lv[1];
            }
            *(h8*)&lds[PXCH_O + tok * 72 + 8 * c4g] = hi;
            *(h8*)&lds[PXCL_O + tok * 72 + 8 * c4g] = lo;
        }
        __syncthreads();
#pragma unroll
        for (int ks = 0; ks < 2; ks++) {
            h8 bxh = *(const h8*)&lds[PXCH_O + (wv * 16 + ln) * 72 + ks * 32 + quad * 8];
            h8 bxl = *(const h8*)&lds[PXCL_O + (wv * 16 + ln) * 72 + ks * 32 + quad * 8];
#pragma unroll
            for (int mt = 0; mt < 4; mt++) {
                h8 wah = *(const h8*)&lds[PWAH_O + (mt * 16 + ln) * 72 + ks * 32 + quad * 8];
                h8 wal = *(const h8*)&lds[PWAL_O + (mt * 16 + ln) * 72 + ks * 32 + quad * 8];
                h8 wbh = rot_neg_lo(wah);
                h8 wbl = rot_neg_lo(wal);
                accR[mt] = MFMA16(wah, bxh, accR[mt]);
                accR[mt] = MFMA16(wah, bxl, accR[mt]);
                accR[mt] = MFMA16(wal, bxh, accR[mt]);
                accI[mt] = MFMA16(wbh, bxh, accI[mt]);
                accI[mt] = MFMA16(wbh, bxl, accI[mt]);
                accI[mt] = MFMA16(wbl, bxh, accI[mt]);
            }
        }
    }

    // epilogue: C[row=ochan(quad*4+r), col=tok(ln)] -> planar f32 out
#pragma unroll
    for (int mt = 0; mt < 4; mt++) {
#pragma unroll
        for (int r = 0; r < 4; r++) {
            int o = qtr * 64 + mt * 16 + quad * 4 + r;
            long long idx = ((long long)(b * 256 + o)) * 64 + wv * 16 + ln;
            if (idx < out_floats)
                out[idx] = accR[mt][r];
            if (PLANE + idx < out_floats)
                out[PLANE + idx] = accI[mt][r];
        }
    }
}

extern "C" void kernel_launch(void* const* d_in, const int* in_sizes, int n_in,
                              void* d_out, int out_size, void* d_ws, size_t ws_size,
                              hipStream_t stream) {
    const float* xr  = (const float*)d_in[0];
    const float* xi  = (const float*)d_in[1];
    const float* wqr = (const float*)d_in[2];
    const float* wqi = (const float*)d_in[3];
    const float* wpr = (const float*)d_in[4];
    const float* wpi = (const float*)d_in[5];
    const float* bt  = (const float*)d_in[6];
    const int*   ri  = (const int*)d_in[7];

    const size_t WSPLIT_BYTES = (size_t)2 * WSPLANE * sizeof(_Float16);   // 2 MiB
    const size_t bytes_per_batch = (size_t)MID_BATCH * sizeof(_Float16); // 128 KiB
    if (ws_size < WSPLIT_BYTES + bytes_per_batch) return;

    _Float16* wsp = (_Float16*)d_ws;
    _Float16* mid = (_Float16*)((char*)d_ws + WSPLIT_BYTES);

    wsplit_kernel<<<256, 256, 0, stream>>>(wqr, wqi, wpr, wpi, wsp);

    size_t chunk_sz = (ws_size - WSPLIT_BYTES) / bytes_per_batch;
    if (chunk_sz > BATCH) chunk_sz = BATCH;
    int chunk = (int)chunk_sz;

    for (int b0 = 0; b0 < BATCH; b0 += chunk) {
        int nb = BATCH - b0;
        if (nb > chunk) nb = chunk;
        attn_kernel<<<nb * NHEADS, 256, 0, stream>>>(xr, xi, wsp, bt, ri, mid, b0);
        proj_kernel<<<nb * 4, 256, 0, stream>>>(wsp, mid, (float*)d_out,
                                                b0, (long long)out_size);
    }
}

// Round 2
// 654.517 us; speedup vs baseline: 2.7570x; 1.3060x over previous
//
#include <hip/hip_runtime.h>
#include <math.h>

#define BATCH 1024
#define CDIM 256
#define NHEADS 8
#define NTOK 64
#define SCALE 0.17677669529663687f  // 32^-0.5

typedef _Float16 h8 __attribute__((ext_vector_type(8)));
typedef _Float16 h2 __attribute__((ext_vector_type(2)));
typedef float f4 __attribute__((ext_vector_type(4)));

#define MFMA16(a, b, c) __builtin_amdgcn_mfma_f32_16x16x32_f16((a), (b), (c), 0, 0, 0)

// ---- workspace layout ----
#define WSPLANE 524288                 // halves per W plane = 1024 * 512
#define WSPLIT_BYTES (2u * WSPLANE * 2u)       // 2 MiB
#define BIAS_FLOATS 32768              // [8][64][64]
#define BIAS_BYTES (BIAS_FLOATS * 4u)  // 128 KiB
#define MID_BATCH 65536                // halves per batch (hi+lo planes)
#define MID_LO    32768

// ---- attn LDS plane offsets (halves) ----
#define WAH_O 0        // [96][72] hi of (wr, -wi)
#define WAL_O 6912     // [96][72] lo
#define XCH_O 13824    // [64][72] hi of (xr, xi)
#define XCL_O 18432    // [64][72] lo                -> ends 23040
// Phase 2+ aliases the dead staging region (barrier-separated):
#define KAH_O 0        // [64][72] hi of (kr, ki)
#define KAL_O 4608     // [64][72] lo
#define VA_O  9216     // [32][136] (vr, -vi) rows = d, cols = 2*tok
#define PC_O  13568    // [64][136] (pr, pi)  rows = query, cols = 2*key
#define A_LDS_HALFS 23040   // 46080 B -> 3 blocks/CU

// ---- proj LDS (halves) ----
#define PWAH_O 0       // [64][72] hi of (wr, -wi)
#define PWAL_O 4608
#define PXCH_O 9216    // [64][72] hi of (or, oi)
#define PXCL_O 13824
#define P_LDS_HALFS 18432   // 36864 B -> 4 blocks/CU

#define PLANE 16777216LL

// split v into f16 hi + f16 lo (residual ~2^-22 relative)
__device__ __forceinline__ void fsplit(float v, _Float16& hi, _Float16& lo) {
    _Float16 hh = (_Float16)v;
    hi = hh;
    lo = (_Float16)(v - (float)hh);
}

// per 32b word (a,b) -> (-b, a)
__device__ __forceinline__ h8 rot_neg_lo(h8 a) {
    union { h8 h; unsigned int w[4]; } u; u.h = a;
#pragma unroll
    for (int i = 0; i < 4; i++) {
        unsigned int t = u.w[i];
        t = (t >> 16) | (t << 16);
        u.w[i] = t ^ 0x00008000u;
    }
    return u.h;
}
// per 32b word (a,b) -> (b, -a)
__device__ __forceinline__ h8 rot_neg_hi(h8 a) {
    union { h8 h; unsigned int w[4]; } u; u.h = a;
#pragma unroll
    for (int i = 0; i < 4; i++) {
        unsigned int t = u.w[i];
        t = (t >> 16) | (t << 16);
        u.w[i] = t ^ 0x80000000u;
    }
    return u.h;
}

// ---------------------------------------------------------------------------
// One-time W pre-split: rows 0..767 = w_qkv, rows 768..1023 = w_proj.
// ---------------------------------------------------------------------------
__global__ __launch_bounds__(256) void wsplit_kernel(
    const float* __restrict__ wqr, const float* __restrict__ wqi,
    const float* __restrict__ wpr, const float* __restrict__ wpi,
    _Float16* __restrict__ wsp)
{
    int g = blockIdx.x * 256 + threadIdx.x;   // 0..65535
    int row = g >> 6;                          // 0..1023 (wave-uniform)
    int c = (g & 63) * 4;
    const float* wrp; const float* wip; int srow;
    if (row < 768) { wrp = wqr; wip = wqi; srow = row; }
    else           { wrp = wpr; wip = wpi; srow = row - 768; }
    float4 r4 = *(const float4*)&wrp[srow * 256 + c];
    float4 i4 = *(const float4*)&wip[srow * 256 + c];
    const float* rp = &r4.x;
    const float* ip = &i4.x;
    h8 hi, lo;
#pragma unroll
    for (int j = 0; j < 4; j++) {
        _Float16 h0, l0, h1, l1;
        fsplit(rp[j], h0, l0);
        fsplit(-ip[j], h1, l1);
        hi[2 * j] = h0; hi[2 * j + 1] = h1;
        lo[2 * j] = l0; lo[2 * j + 1] = l1;
    }
    *(h8*)&wsp[(size_t)row * 512 + 2 * c] = hi;
    *(h8*)&wsp[WSPLANE + (size_t)row * 512 + 2 * c] = lo;
}

// ---------------------------------------------------------------------------
// One-time bias expansion: bias_full[h][qrow][mcol] = bt[ri[qrow*64+mcol]*8+h]
// ---------------------------------------------------------------------------
__global__ __launch_bounds__(256) void bias_kernel(
    const float* __restrict__ bt, const int* __restrict__ ri,
    float* __restrict__ bias_full)
{
    int g = blockIdx.x * 256 + threadIdx.x;   // 0..32767
    int hh = g >> 12;
    int pos = g & 4095;
    bias_full[g] = bt[ri[pos] * 8 + hh];
}

// ---------------------------------------------------------------------------
// MFMA attention kernel: one block per (local-batch, head), 256 thr = 4 waves.
// Rot-on-B complex arithmetic; T14 async staging; Q kept in registers.
// ---------------------------------------------------------------------------
__global__ __launch_bounds__(256) void attn_kernel(
    const float* __restrict__ xr, const float* __restrict__ xi,
    const _Float16* __restrict__ wsp,
    const float* __restrict__ bias_full,
    _Float16* __restrict__ mid, int b0)
{
    const int blk = blockIdx.x;
    // XCD swizzle: all 8 head-blocks of a batch on the same XCD (blk%8).
    int bl, h;
    if ((gridDim.x & 63) == 0) {
        int xcd = blk & 7;
        int slot = blk >> 3;
        h  = slot & 7;
        bl = ((slot >> 3) << 3) | xcd;
    } else { bl = blk >> 3; h = blk & 7; }
    const int b  = b0 + bl;
    const int t  = threadIdx.x;
    const int ln   = t & 15;         // frag 16-index
    const int quad = (t >> 4) & 3;   // frag k-quad
    const int wv   = t >> 6;         // wave id = token-group

    __shared__ alignas(16) _Float16 lds[A_LDS_HALFS];

    // ---- Phase 1: QKV projection. acc tiles: mt 0,1=q 2,3=k 4,5=v
    f4 accR[6], accI[6];
#pragma unroll
    for (int m = 0; m < 6; m++) {
        accR[m] = (f4){0.f, 0.f, 0.f, 0.f};
        accI[m] = (f4){0.f, 0.f, 0.f, 0.f};
    }

    // hoisted staging coordinates
    int wrow[3], wc4[3], wgrow[3];
#pragma unroll
    for (int i = 0; i < 3; i++) {
        int p = t + i * 256;
        int row = p >> 3;
        wrow[i] = row; wc4[i] = p & 7;
        wgrow[i] = (row < 32) ? (h * 32 + row)
                 : (row < 64) ? (256 + h * 32 + (row - 32))
                              : (512 + h * 32 + (row - 64));
    }
    int xtok[2], xc4g[2];
#pragma unroll
    for (int i = 0; i < 2; i++) {
        int p = t + i * 256;
        xtok[i] = p & 63; xc4g[i] = p >> 6;
    }

    h8 wpre[3][2];
    float xpreR[2][4], xpreI[2][4];

    auto load_chunk = [&](int ch) {
#pragma unroll
        for (int i = 0; i < 3; i++) {
            const _Float16* wp = &wsp[(size_t)wgrow[i] * 512 + ch * 64 + wc4[i] * 8];
            wpre[i][0] = *(const h8*)wp;
            wpre[i][1] = *(const h8*)(wp + WSPLANE);
        }
#pragma unroll
        for (int i = 0; i < 2; i++) {
            int c = ch * 32 + xc4g[i] * 4;
#pragma unroll
            for (int j = 0; j < 4; j++) {
                xpreR[i][j] = xr[(b * 256 + c + j) * 64 + xtok[i]];
                xpreI[i][j] = xi[(b * 256 + c + j) * 64 + xtok[i]];
            }
        }
    };

    load_chunk(0);

    for (int chunk = 0; chunk < 8; chunk++) {
        __syncthreads();     // previous MFMA done reading LDS
        // write staged registers to LDS
#pragma unroll
        for (int i = 0; i < 3; i++) {
            *(h8*)&lds[WAH_O + wrow[i] * 72 + 8 * wc4[i]] = wpre[i][0];
            *(h8*)&lds[WAL_O + wrow[i] * 72 + 8 * wc4[i]] = wpre[i][1];
        }
#pragma unroll
        for (int i = 0; i < 2; i++) {
            h8 hi, lo;
#pragma unroll
            for (int j = 0; j < 4; j++) {
                _Float16 h0, l0, h1, l1;
                fsplit(xpreR[i][j], h0, l0);
                fsplit(xpreI[i][j], h1, l1);
                hi[2 * j] = h0; hi[2 * j + 1] = h1;
                lo[2 * j] = l0; lo[2 * j + 1] = l1;
            }
            *(h8*)&lds[XCH_O + xtok[i] * 72 + 8 * xc4g[i]] = hi;
            *(h8*)&lds[XCL_O + xtok[i] * 72 + 8 * xc4g[i]] = lo;
        }
        __syncthreads();     // LDS ready
        if (chunk < 7) load_chunk(chunk + 1);  // prefetch hides under MFMA

#pragma unroll
        for (int ks = 0; ks < 2; ks++) {
            h8 bxh = *(const h8*)&lds[XCH_O + (wv * 16 + ln) * 72 + ks * 32 + quad * 8];
            h8 bxl = *(const h8*)&lds[XCL_O + (wv * 16 + ln) * 72 + ks * 32 + quad * 8];
            h8 rxh = rot_neg_hi(bxh);   // (xi, -xr)
            h8 rxl = rot_neg_hi(bxl);
#pragma unroll
            for (int mt = 0; mt < 6; mt++) {
                h8 wah = *(const h8*)&lds[WAH_O + (mt * 16 + ln) * 72 + ks * 32 + quad * 8];
                h8 wal = *(const h8*)&lds[WAL_O + (mt * 16 + ln) * 72 + ks * 32 + quad * 8];
                accR[mt] = MFMA16(wah, bxh, accR[mt]);
                accR[mt] = MFMA16(wah, bxl, accR[mt]);
                accR[mt] = MFMA16(wal, bxh, accR[mt]);
                accI[mt] = MFMA16(wah, rxh, accI[mt]);
                accI[mt] = MFMA16(wah, rxl, accI[mt]);
                accI[mt] = MFMA16(wal, rxh, accI[mt]);
            }
        }
    }
    __syncthreads();

    // ---- Phase 2: scatter k (split hi/lo) and v (single f16) to LDS.
    {
        const int tok = wv * 16 + ln;
#pragma unroll
        for (int mt = 2; mt < 4; mt++) {
            int d0 = (mt - 2) * 16 + quad * 4;
            h8 hi, lo;
#pragma unroll
            for (int r = 0; r < 4; r++) {
                _Float16 h0, l0, h1, l1;
                fsplit(accR[mt][r], h0, l0);
                fsplit(accI[mt][r], h1, l1);
                hi[2 * r] = h0; hi[2 * r + 1] = h1;
                lo[2 * r] = l0; lo[2 * r + 1] = l1;
            }
            *(h8*)&lds[KAH_O + tok * 72 + 2 * d0] = hi;
            *(h8*)&lds[KAL_O + tok * 72 + 2 * d0] = lo;
        }
#pragma unroll
        for (int mt = 4; mt < 6; mt++) {
#pragma unroll
            for (int r = 0; r < 4; r++) {
                int d = (mt - 4) * 16 + quad * 4 + r;
                h2 va = {(_Float16)accR[mt][r], (_Float16)(-accI[mt][r])};
                *(h2*)&lds[VA_O + d * 136 + 2 * tok] = va;
            }
        }
    }
    __syncthreads();

    // ---- Phase 3: S = scale*(Q conj(K)^H) + bias; magnitude softmax; P -> LDS
    {
        f4 sR[4], sI[4];
#pragma unroll
        for (int m = 0; m < 4; m++) {
            sR[m] = (f4){0.f, 0.f, 0.f, 0.f};
            sI[m] = (f4){0.f, 0.f, 0.f, 0.f};
        }
#pragma unroll
        for (int ks = 0; ks < 2; ks++) {
            // Q fragment built in-register from phase-1 acc (mt = ks)
            h8 qh, ql;
#pragma unroll
            for (int r = 0; r < 4; r++) {
                _Float16 h0, l0, h1, l1;
                fsplit(accR[ks][r], h0, l0);
                fsplit(accI[ks][r], h1, l1);
                qh[2 * r] = h0; qh[2 * r + 1] = h1;
                ql[2 * r] = l0; ql[2 * r + 1] = l1;
            }
            h8 qbh = rot_neg_hi(qh);   // (qi, -qr)
            h8 qbl = rot_neg_hi(ql);
#pragma unroll
            for (int mt = 0; mt < 4; mt++) {
                h8 kh = *(const h8*)&lds[KAH_O + (mt * 16 + ln) * 72 + ks * 32 + quad * 8];
                h8 kl = *(const h8*)&lds[KAL_O + (mt * 16 + ln) * 72 + ks * 32 + quad * 8];
                sR[mt] = MFMA16(qh, kh, sR[mt]);
                sR[mt] = MFMA16(qh, kl, sR[mt]);
                sR[mt] = MFMA16(ql, kh, sR[mt]);
                sI[mt] = MFMA16(qbh, kh, sI[mt]);
                sI[mt] = MFMA16(qbh, kl, sI[mt]);
                sI[mt] = MFMA16(qbl, kh, sI[mt]);
            }
        }
        const float* bfh = &bias_full[h * 4096];
#pragma unroll
        for (int r = 0; r < 4; r++) {
            int qrow = wv * 16 + quad * 4 + r;
            float pr[4], pi[4], mg[4], e[4];
            float mx = -1e30f;
#pragma unroll
            for (int mt = 0; mt < 4; mt++) {
                int mcol = mt * 16 + ln;
                float bias = bfh[qrow * 64 + mcol];
                float srv = sR[mt][r] * SCALE + bias;
                float siv = sI[mt][r] * SCALE;
                pr[mt] = srv; pi[mt] = siv;
                mg[mt] = __builtin_amdgcn_sqrtf(srv * srv + siv * siv);
                mx = fmaxf(mx, mg[mt]);
            }
            mx = fmaxf(mx, __shfl_xor(mx, 1));
            mx = fmaxf(mx, __shfl_xor(mx, 2));
            mx = fmaxf(mx, __shfl_xor(mx, 4));
            mx = fmaxf(mx, __shfl_xor(mx, 8));
            float se = 0.f;
#pragma unroll
            for (int mt = 0; mt < 4; mt++) { e[mt] = __expf(mg[mt] - mx); se += e[mt]; }
            se += __shfl_xor(se, 1);
            se += __shfl_xor(se, 2);
            se += __shfl_xor(se, 4);
            se += __shfl_xor(se, 8);
            float inv = __builtin_amdgcn_rcpf(se);
#pragma unroll
            for (int mt = 0; mt < 4; mt++) {
                float f = e[mt] * inv * __builtin_amdgcn_rcpf(mg[mt] + 1e-8f);
                h2 p = {(_Float16)(pr[mt] * f), (_Float16)(pi[mt] * f)};
                *(h2*)&lds[PC_O + qrow * 136 + 2 * (mt * 16 + ln)] = p;
            }
        }
    }
    __syncthreads();

    // ---- Phase 4: O = P V (complex); rotate P once instead of V twice
    {
        f4 oR[2], oI[2];
#pragma unroll
        for (int m = 0; m < 2; m++) {
            oR[m] = (f4){0.f, 0.f, 0.f, 0.f};
            oI[m] = (f4){0.f, 0.f, 0.f, 0.f};
        }
#pragma unroll
        for (int ks = 0; ks < 4; ks++) {
            h8 ap = *(const h8*)&lds[PC_O + (wv * 16 + ln) * 136 + ks * 32 + quad * 8];
            h8 apn = rot_neg_hi(ap);   // (pi, -pr)
#pragma unroll
            for (int dt = 0; dt < 2; dt++) {
                h8 va = *(const h8*)&lds[VA_O + (dt * 16 + ln) * 136 + ks * 32 + quad * 8];
                oR[dt] = MFMA16(ap, va, oR[dt]);
                oI[dt] = MFMA16(apn, va, oI[dt]);
            }
        }
        _Float16* mB = mid + (size_t)bl * MID_BATCH;
#pragma unroll
        for (int dt = 0; dt < 2; dt++) {
            int c = h * 32 + dt * 16 + ln;
            int tbase = wv * 16 + quad * 4;
            h8 hv, lv;
#pragma unroll
            for (int r = 0; r < 4; r++) {
                _Float16 hr, lr, hx, lx;
                fsplit(oR[dt][r], hr, lr);
                fsplit(oI[dt][r], hx, lx);
                hv[2 * r] = hr; hv[2 * r + 1] = hx;
                lv[2 * r] = lr; lv[2 * r + 1] = lx;
            }
            *(h8*)&mB[(size_t)(c * 64 + tbase) * 2] = hv;
            *(h8*)&mB[MID_LO + (size_t)(c * 64 + tbase) * 2] = lv;
        }
    }
}

// ---------------------------------------------------------------------------
// Proj kernel, MFMA split-f16, rot-on-B, T14 async staging.
// ---------------------------------------------------------------------------
__global__ __launch_bounds__(256) void proj_kernel(
    const _Float16* __restrict__ wsp,
    const _Float16* __restrict__ mid,
    float* __restrict__ out, int b0, long long out_floats)
{
    const int blk = blockIdx.x;
    int bl, qtr;
    if ((gridDim.x & 31) == 0) {
        int xcd = blk & 7;
        int slot = blk >> 3;
        qtr = slot & 3;
        bl  = ((slot >> 2) << 3) | xcd;
    } else { bl = blk >> 2; qtr = blk & 3; }
    const int b  = b0 + bl;
    const int t  = threadIdx.x;
    const int ln   = t & 15;
    const int quad = (t >> 4) & 3;
    const int wv   = t >> 6;

    __shared__ alignas(16) _Float16 lds[P_LDS_HALFS];
    const _Float16* mB = mid + (size_t)bl * MID_BATCH;

    f4 accR[4], accI[4];
#pragma unroll
    for (int m = 0; m < 4; m++) {
        accR[m] = (f4){0.f, 0.f, 0.f, 0.f};
        accI[m] = (f4){0.f, 0.f, 0.f, 0.f};
    }

    // hoisted staging coordinates
    int prow[2], pc4[2], ptok[2], pcg[2];
#pragma unroll
    for (int i = 0; i < 2; i++) {
        int p = t + i * 256;
        prow[i] = p >> 3; pc4[i] = p & 7;
        ptok[i] = p & 63; pcg[i] = p >> 6;
    }

    h8 wpre[2][2];
    unsigned int mpreH[2][4], mpreL[2][4];

    auto load_chunk = [&](int ch) {
#pragma unroll
        for (int i = 0; i < 2; i++) {
            int grow = 768 + qtr * 64 + prow[i];
            const _Float16* wp = &wsp[(size_t)grow * 512 + ch * 64 + pc4[i] * 8];
            wpre[i][0] = *(const h8*)wp;
            wpre[i][1] = *(const h8*)(wp + WSPLANE);
        }
#pragma unroll
        for (int i = 0; i < 2; i++) {
            int c = ch * 32 + pcg[i] * 4;
#pragma unroll
            for (int j = 0; j < 4; j++) {
                mpreH[i][j] = *(const unsigned int*)&mB[(size_t)((c + j) * 64 + ptok[i]) * 2];
                mpreL[i][j] = *(const unsigned int*)&mB[MID_LO + (size_t)((c + j) * 64 + ptok[i]) * 2];
            }
        }
    };

    load_chunk(0);

    for (int chunk = 0; chunk < 8; chunk++) {
        __syncthreads();
#pragma unroll
        for (int i = 0; i < 2; i++) {
            *(h8*)&lds[PWAH_O + prow[i] * 72 + 8 * pc4[i]] = wpre[i][0];
            *(h8*)&lds[PWAL_O + prow[i] * 72 + 8 * pc4[i]] = wpre[i][1];
        }
#pragma unroll
        for (int i = 0; i < 2; i++) {
            union { h8 v; unsigned int w[4]; } hu, lu;
#pragma unroll
            for (int j = 0; j < 4; j++) { hu.w[j] = mpreH[i][j]; lu.w[j] = mpreL[i][j]; }
            *(h8*)&lds[PXCH_O + ptok[i] * 72 + 8 * pcg[i]] = hu.v;
            *(h8*)&lds[PXCL_O + ptok[i] * 72 + 8 * pcg[i]] = lu.v;
        }
        __syncthreads();
        if (chunk < 7) load_chunk(chunk + 1);

#pragma unroll
        for (int ks = 0; ks < 2; ks++) {
            h8 bxh = *(const h8*)&lds[PXCH_O + (wv * 16 + ln) * 72 + ks * 32 + quad * 8];
            h8 bxl = *(const h8*)&lds[PXCL_O + (wv * 16 + ln) * 72 + ks * 32 + quad * 8];
            h8 rxh = rot_neg_hi(bxh);
            h8 rxl = rot_neg_hi(bxl);
#pragma unroll
            for (int mt = 0; mt < 4; mt++) {
                h8 wah = *(const h8*)&lds[PWAH_O + (mt * 16 + ln) * 72 + ks * 32 + quad * 8];
                h8 wal = *(const h8*)&lds[PWAL_O + (mt * 16 + ln) * 72 + ks * 32 + quad * 8];
                accR[mt] = MFMA16(wah, bxh, accR[mt]);
                accR[mt] = MFMA16(wah, bxl, accR[mt]);
                accR[mt] = MFMA16(wal, bxh, accR[mt]);
                accI[mt] = MFMA16(wah, rxh, accI[mt]);
                accI[mt] = MFMA16(wah, rxl, accI[mt]);
                accI[mt] = MFMA16(wal, rxh, accI[mt]);
            }
        }
    }

    // epilogue: planar f32 out
#pragma unroll
    for (int mt = 0; mt < 4; mt++) {
#pragma unroll
        for (int r = 0; r < 4; r++) {
            int o = qtr * 64 + mt * 16 + quad * 4 + r;
            long long idx = ((long long)(b * 256 + o)) * 64 + wv * 16 + ln;
            if (idx < out_floats)
                out[idx] = accR[mt][r];
            if (PLANE + idx < out_floats)
                out[PLANE + idx] = accI[mt][r];
        }
    }
}

extern "C" void kernel_launch(void* const* d_in, const int* in_sizes, int n_in,
                              void* d_out, int out_size, void* d_ws, size_t ws_size,
                              hipStream_t stream) {
    const float* xr  = (const float*)d_in[0];
    const float* xi  = (const float*)d_in[1];
    const float* wqr = (const float*)d_in[2];
    const float* wqi = (const float*)d_in[3];
    const float* wpr = (const float*)d_in[4];
    const float* wpi = (const float*)d_in[5];
    const float* bt  = (const float*)d_in[6];
    const int*   ri  = (const int*)d_in[7];

    const size_t bytes_per_batch = (size_t)MID_BATCH * sizeof(_Float16); // 128 KiB
    const size_t head_bytes = (size_t)WSPLIT_BYTES + BIAS_BYTES;
    if (ws_size < head_bytes + bytes_per_batch) return;

    _Float16* wsp  = (_Float16*)d_ws;
    float*    bsf  = (float*)((char*)d_ws + WSPLIT_BYTES);
    _Float16* mid  = (_Float16*)((char*)d_ws + head_bytes);

    wsplit_kernel<<<256, 256, 0, stream>>>(wqr, wqi, wpr, wpi, wsp);
    bias_kernel<<<128, 256, 0, stream>>>(bt, ri, bsf);

    size_t chunk_sz = (ws_size - head_bytes) / bytes_per_batch;
    if (chunk_sz > BATCH) chunk_sz = BATCH;
    int chunk = (int)chunk_sz;

    for (int b0 = 0; b0 < BATCH; b0 += chunk) {
        int nb = BATCH - b0;
        if (nb > chunk) nb = chunk;
        attn_kernel<<<nb * NHEADS, 256, 0, stream>>>(xr, xi, wsp, bsf, mid, b0);
        proj_kernel<<<nb * 4, 256, 0, stream>>>(wsp, mid, (float*)d_out,
                                                b0, (long long)out_size);
    }
}

// Round 3
// 567.547 us; speedup vs baseline: 3.1795x; 1.1532x over previous
//
#include <hip/hip_runtime.h>
#include <math.h>

#define BATCH 1024
#define CDIM 256
#define NHEADS 8
#define NTOK 64
#define SCALE 0.17677669529663687f  // 32^-0.5

typedef _Float16 h8 __attribute__((ext_vector_type(8)));
typedef _Float16 h2 __attribute__((ext_vector_type(2)));
typedef float f4 __attribute__((ext_vector_type(4)));

#define MFMA16(a, b, c) __builtin_amdgcn_mfma_f32_16x16x32_f16((a), (b), (c), 0, 0, 0)

// ---- workspace layout ----
#define WSPLANE 524288                 // halves per W plane = 1024 * 512
#define WSPLIT_BYTES (2u * WSPLANE * 2u)       // 2 MiB
#define BIAS_FLOATS 32768              // [8][64][64]
#define BIAS_BYTES (BIAS_FLOATS * 4u)  // 128 KiB
#define MID_BATCH 65536                // halves per batch (hi+lo planes)
#define MID_LO    32768

// ---- attn LDS plane offsets (halves), stride-64/128 + XOR block swizzle ----
// Phase 1 staging:
#define WAH_O 0        // [96][64] hi of (wr, -wi)
#define WAL_O 6144     // [96][64] lo
#define XCH_O 12288    // [64][64] hi of (xr, xi)
#define XCL_O 16384    // [64][64] lo                -> ends 20480
// Phase 2+ aliases the dead staging region (barrier-separated):
#define KAH_O 0        // [64][64] hi of (kr, ki)
#define KAL_O 4096     // [64][64] lo
#define VA_O  8192     // [32][128] (vr, -vi) rows = d, cols = 2*tok
#define PC_O  12288    // [64][128] (pr, pi)  rows = query, cols = 2*key
#define A_LDS_HALFS 20480   // 40960 B -> exactly 4 blocks/CU

// ---- proj LDS (halves) ----
#define PWAH_O 0       // [64][64] hi of (wr, -wi)
#define PWAL_O 4096
#define PXCH_O 8192    // [64][64] hi of (or, oi)
#define PXCL_O 12288
#define P_LDS_HALFS 16384   // 32768 B -> 5 blocks/CU

#define PLANE 16777216LL

// split v into f16 hi + f16 lo (residual ~2^-22 relative)
__device__ __forceinline__ void fsplit(float v, _Float16& hi, _Float16& lo) {
    _Float16 hh = (_Float16)v;
    hi = hh;
    lo = (_Float16)(v - (float)hh);
}

// per 32b word (a,b) -> (b, -a)
__device__ __forceinline__ h8 rot_neg_hi(h8 a) {
    union { h8 h; unsigned int w[4]; } u; u.h = a;
#pragma unroll
    for (int i = 0; i < 4; i++) {
        unsigned int t = u.w[i];
        t = (t >> 16) | (t << 16);
        u.w[i] = t ^ 0x80000000u;
    }
    return u.h;
}

// ---------------------------------------------------------------------------
// One-time W pre-split: rows 0..767 = w_qkv, rows 768..1023 = w_proj.
// ---------------------------------------------------------------------------
__global__ __launch_bounds__(256) void wsplit_kernel(
    const float* __restrict__ wqr, const float* __restrict__ wqi,
    const float* __restrict__ wpr, const float* __restrict__ wpi,
    _Float16* __restrict__ wsp)
{
    int g = blockIdx.x * 256 + threadIdx.x;   // 0..65535
    int row = g >> 6;                          // 0..1023 (wave-uniform)
    int c = (g & 63) * 4;
    const float* wrp; const float* wip; int srow;
    if (row < 768) { wrp = wqr; wip = wqi; srow = row; }
    else           { wrp = wpr; wip = wpi; srow = row - 768; }
    float4 r4 = *(const float4*)&wrp[srow * 256 + c];
    float4 i4 = *(const float4*)&wip[srow * 256 + c];
    const float* rp = &r4.x;
    const float* ip = &i4.x;
    h8 hi, lo;
#pragma unroll
    for (int j = 0; j < 4; j++) {
        _Float16 h0, l0, h1, l1;
        fsplit(rp[j], h0, l0);
        fsplit(-ip[j], h1, l1);
        hi[2 * j] = h0; hi[2 * j + 1] = h1;
        lo[2 * j] = l0; lo[2 * j + 1] = l1;
    }
    *(h8*)&wsp[(size_t)row * 512 + 2 * c] = hi;
    *(h8*)&wsp[WSPLANE + (size_t)row * 512 + 2 * c] = lo;
}

// ---------------------------------------------------------------------------
// One-time bias expansion: bias_full[h][qrow][mcol] = bt[ri[qrow*64+mcol]*8+h]
// ---------------------------------------------------------------------------
__global__ __launch_bounds__(256) void bias_kernel(
    const float* __restrict__ bt, const int* __restrict__ ri,
    float* __restrict__ bias_full)
{
    int g = blockIdx.x * 256 + threadIdx.x;   // 0..32767
    int hh = g >> 12;
    int pos = g & 4095;
    bias_full[g] = bt[ri[pos] * 8 + hh];
}

// ---------------------------------------------------------------------------
// MFMA attention kernel: one block per (local-batch, head), 256 thr = 4 waves.
// Stride-64 LDS + XOR block swizzle -> 40960 B LDS, 4 blocks/CU.
// ---------------------------------------------------------------------------
__global__ __launch_bounds__(256) void attn_kernel(
    const float* __restrict__ xr, const float* __restrict__ xi,
    const _Float16* __restrict__ wsp,
    const float* __restrict__ bias_full,
    _Float16* __restrict__ mid, int b0)
{
    const int blk = blockIdx.x;
    // XCD swizzle: all 8 head-blocks of a batch on the same XCD (blk%8).
    int bl, h;
    if ((gridDim.x & 63) == 0) {
        int xcd = blk & 7;
        int slot = blk >> 3;
        h  = slot & 7;
        bl = ((slot >> 3) << 3) | xcd;
    } else { bl = blk >> 3; h = blk & 7; }
    const int b  = b0 + bl;
    const int t  = threadIdx.x;
    const int ln   = t & 15;         // frag 16-index
    const int quad = (t >> 4) & 3;   // frag k-quad
    const int wv   = t >> 6;         // wave id = token-group
    const int lnk  = ln & 7;         // swizzle key for fragment reads

    __shared__ alignas(16) _Float16 lds[A_LDS_HALFS];

    // ---- Phase 1: QKV projection. acc tiles: mt 0,1=q 2,3=k 4,5=v
    f4 accR[6], accI[6];
#pragma unroll
    for (int m = 0; m < 6; m++) {
        accR[m] = (f4){0.f, 0.f, 0.f, 0.f};
        accI[m] = (f4){0.f, 0.f, 0.f, 0.f};
    }

    // hoisted staging coordinates (with swizzled LDS offsets)
    int wlds[3], wgrow[3];
#pragma unroll
    for (int i = 0; i < 3; i++) {
        int p = t + i * 256;
        int row = p >> 3, c4 = p & 7;
        wgrow[i] = (row < 32) ? (h * 32 + row)
                 : (row < 64) ? (256 + h * 32 + (row - 32))
                              : (512 + h * 32 + (row - 64));
        wlds[i] = row * 64 + ((c4 ^ (row & 7)) << 3);
    }
    int xtok[2], xc4g[2], xlds[2];
#pragma unroll
    for (int i = 0; i < 2; i++) {
        int p = t + i * 256;
        xtok[i] = p & 63; xc4g[i] = p >> 6;
        xlds[i] = xtok[i] * 64 + ((xc4g[i] ^ (xtok[i] & 7)) << 3);
    }
    int wc4[3];
#pragma unroll
    for (int i = 0; i < 3; i++) wc4[i] = (t + i * 256) & 7;

    h8 wpre[3][2];
    float xpreR[2][4], xpreI[2][4];

    auto load_chunk = [&](int ch) {
#pragma unroll
        for (int i = 0; i < 3; i++) {
            const _Float16* wp = &wsp[(size_t)wgrow[i] * 512 + ch * 64 + wc4[i] * 8];
            wpre[i][0] = *(const h8*)wp;
            wpre[i][1] = *(const h8*)(wp + WSPLANE);
        }
#pragma unroll
        for (int i = 0; i < 2; i++) {
            int c = ch * 32 + xc4g[i] * 4;
#pragma unroll
            for (int j = 0; j < 4; j++) {
                xpreR[i][j] = xr[(b * 256 + c + j) * 64 + xtok[i]];
                xpreI[i][j] = xi[(b * 256 + c + j) * 64 + xtok[i]];
            }
        }
    };

    load_chunk(0);

    // bias prefetch (L2-resident table; issue early, consume in phase 3)
    float bpre[4][4];
    {
        const float* bfh = &bias_full[h * 4096];
#pragma unroll
        for (int r = 0; r < 4; r++) {
            int qrow = wv * 16 + quad * 4 + r;
#pragma unroll
            for (int mt = 0; mt < 4; mt++)
                bpre[r][mt] = bfh[qrow * 64 + mt * 16 + ln];
        }
    }

    for (int chunk = 0; chunk < 8; chunk++) {
        __syncthreads();     // previous MFMA done reading LDS
#pragma unroll
        for (int i = 0; i < 3; i++) {
            *(h8*)&lds[WAH_O + wlds[i]] = wpre[i][0];
            *(h8*)&lds[WAL_O + wlds[i]] = wpre[i][1];
        }
#pragma unroll
        for (int i = 0; i < 2; i++) {
            h8 hi, lo;
#pragma unroll
            for (int j = 0; j < 4; j++) {
                _Float16 h0, l0, h1, l1;
                fsplit(xpreR[i][j], h0, l0);
                fsplit(xpreI[i][j], h1, l1);
                hi[2 * j] = h0; hi[2 * j + 1] = h1;
                lo[2 * j] = l0; lo[2 * j + 1] = l1;
            }
            *(h8*)&lds[XCH_O + xlds[i]] = hi;
            *(h8*)&lds[XCL_O + xlds[i]] = lo;
        }
        __syncthreads();     // LDS ready
        if (chunk < 7) load_chunk(chunk + 1);  // prefetch hides under MFMA

#pragma unroll
        for (int ks = 0; ks < 2; ks++) {
            int fblk = ((ks * 4 + quad) ^ lnk) << 3;
            h8 bxh = *(const h8*)&lds[XCH_O + (wv * 16 + ln) * 64 + fblk];
            h8 bxl = *(const h8*)&lds[XCL_O + (wv * 16 + ln) * 64 + fblk];
            h8 rxh = rot_neg_hi(bxh);   // (xi, -xr)
            h8 rxl = rot_neg_hi(bxl);
#pragma unroll
            for (int mt = 0; mt < 6; mt++) {
                h8 wah = *(const h8*)&lds[WAH_O + (mt * 16 + ln) * 64 + fblk];
                h8 wal = *(const h8*)&lds[WAL_O + (mt * 16 + ln) * 64 + fblk];
                accR[mt] = MFMA16(wah, bxh, accR[mt]);
                accR[mt] = MFMA16(wah, bxl, accR[mt]);
                accR[mt] = MFMA16(wal, bxh, accR[mt]);
                accI[mt] = MFMA16(wah, rxh, accI[mt]);
                accI[mt] = MFMA16(wah, rxl, accI[mt]);
                accI[mt] = MFMA16(wal, rxh, accI[mt]);
            }
        }
    }
    __syncthreads();

    // ---- Phase 2: scatter k (split hi/lo) and v (single f16) to LDS.
    {
        const int tok = wv * 16 + ln;
#pragma unroll
        for (int mt = 2; mt < 4; mt++) {
            int cblk = ((mt - 2) * 4 + quad) ^ (tok & 7);
            h8 hi, lo;
#pragma unroll
            for (int r = 0; r < 4; r++) {
                _Float16 h0, l0, h1, l1;
                fsplit(accR[mt][r], h0, l0);
                fsplit(accI[mt][r], h1, l1);
                hi[2 * r] = h0; hi[2 * r + 1] = h1;
                lo[2 * r] = l0; lo[2 * r + 1] = l1;
            }
            *(h8*)&lds[KAH_O + tok * 64 + (cblk << 3)] = hi;
            *(h8*)&lds[KAL_O + tok * 64 + (cblk << 3)] = lo;
        }
#pragma unroll
        for (int mt = 4; mt < 6; mt++) {
#pragma unroll
            for (int r = 0; r < 4; r++) {
                int d = (mt - 4) * 16 + quad * 4 + r;
                int vblk = (tok >> 2) ^ (d & 7);
                h2 va = {(_Float16)accR[mt][r], (_Float16)(-accI[mt][r])};
                *(h2*)&lds[VA_O + d * 128 + (vblk << 3) + 2 * (tok & 3)] = va;
            }
        }
    }
    __syncthreads();

    // ---- Phase 3: S = scale*(Q conj(K)^H) + bias; magnitude softmax; P -> LDS
    {
        f4 sR[4], sI[4];
#pragma unroll
        for (int m = 0; m < 4; m++) {
            sR[m] = (f4){0.f, 0.f, 0.f, 0.f};
            sI[m] = (f4){0.f, 0.f, 0.f, 0.f};
        }
#pragma unroll
        for (int ks = 0; ks < 2; ks++) {
            // Q fragment built in-register from phase-1 acc (mt = ks)
            h8 qh, ql;
#pragma unroll
            for (int r = 0; r < 4; r++) {
                _Float16 h0, l0, h1, l1;
                fsplit(accR[ks][r], h0, l0);
                fsplit(accI[ks][r], h1, l1);
                qh[2 * r] = h0; qh[2 * r + 1] = h1;
                ql[2 * r] = l0; ql[2 * r + 1] = l1;
            }
            h8 qbh = rot_neg_hi(qh);   // (qi, -qr)
            h8 qbl = rot_neg_hi(ql);
            int fblk = ((ks * 4 + quad) ^ lnk) << 3;
#pragma unroll
            for (int mt = 0; mt < 4; mt++) {
                h8 kh = *(const h8*)&lds[KAH_O + (mt * 16 + ln) * 64 + fblk];
                h8 kl = *(const h8*)&lds[KAL_O + (mt * 16 + ln) * 64 + fblk];
                sR[mt] = MFMA16(qh, kh, sR[mt]);
                sR[mt] = MFMA16(qh, kl, sR[mt]);
                sR[mt] = MFMA16(ql, kh, sR[mt]);
                sI[mt] = MFMA16(qbh, kh, sI[mt]);
                sI[mt] = MFMA16(qbh, kl, sI[mt]);
                sI[mt] = MFMA16(qbl, kh, sI[mt]);
            }
        }
#pragma unroll
        for (int r = 0; r < 4; r++) {
            int qrow = wv * 16 + quad * 4 + r;
            float pr[4], pi[4], mg[4], e[4];
            float mx = -1e30f;
#pragma unroll
            for (int mt = 0; mt < 4; mt++) {
                float bias = bpre[r][mt];
                float srv = sR[mt][r] * SCALE + bias;
                float siv = sI[mt][r] * SCALE;
                pr[mt] = srv; pi[mt] = siv;
                mg[mt] = __builtin_amdgcn_sqrtf(srv * srv + siv * siv);
                mx = fmaxf(mx, mg[mt]);
            }
            mx = fmaxf(mx, __shfl_xor(mx, 1));
            mx = fmaxf(mx, __shfl_xor(mx, 2));
            mx = fmaxf(mx, __shfl_xor(mx, 4));
            mx = fmaxf(mx, __shfl_xor(mx, 8));
            float se = 0.f;
#pragma unroll
            for (int mt = 0; mt < 4; mt++) { e[mt] = __expf(mg[mt] - mx); se += e[mt]; }
            se += __shfl_xor(se, 1);
            se += __shfl_xor(se, 2);
            se += __shfl_xor(se, 4);
            se += __shfl_xor(se, 8);
            float inv = __builtin_amdgcn_rcpf(se);
            int qk = qrow & 7;
#pragma unroll
            for (int mt = 0; mt < 4; mt++) {
                float f = e[mt] * inv * __builtin_amdgcn_rcpf(mg[mt] + 1e-8f);
                h2 p = {(_Float16)(pr[mt] * f), (_Float16)(pi[mt] * f)};
                int pblk = (mt * 4 + (ln >> 2)) ^ qk;
                *(h2*)&lds[PC_O + qrow * 128 + (pblk << 3) + 2 * (ln & 3)] = p;
            }
        }
    }
    __syncthreads();

    // ---- Phase 4: O = P V (complex); rotate P once instead of V twice
    {
        f4 oR[2], oI[2];
#pragma unroll
        for (int m = 0; m < 2; m++) {
            oR[m] = (f4){0.f, 0.f, 0.f, 0.f};
            oI[m] = (f4){0.f, 0.f, 0.f, 0.f};
        }
#pragma unroll
        for (int ks = 0; ks < 4; ks++) {
            int fblk = ((ks * 4 + quad) ^ lnk) << 3;
            h8 ap = *(const h8*)&lds[PC_O + (wv * 16 + ln) * 128 + fblk];
            h8 apn = rot_neg_hi(ap);   // (pi, -pr)
#pragma unroll
            for (int dt = 0; dt < 2; dt++) {
                h8 va = *(const h8*)&lds[VA_O + (dt * 16 + ln) * 128 + fblk];
                oR[dt] = MFMA16(ap, va, oR[dt]);
                oI[dt] = MFMA16(apn, va, oI[dt]);
            }
        }
        _Float16* mB = mid + (size_t)bl * MID_BATCH;
#pragma unroll
        for (int dt = 0; dt < 2; dt++) {
            int c = h * 32 + dt * 16 + ln;
            int tbase = wv * 16 + quad * 4;
            h8 hv, lv;
#pragma unroll
            for (int r = 0; r < 4; r++) {
                _Float16 hr, lr, hx, lx;
                fsplit(oR[dt][r], hr, lr);
                fsplit(oI[dt][r], hx, lx);
                hv[2 * r] = hr; hv[2 * r + 1] = hx;
                lv[2 * r] = lr; lv[2 * r + 1] = lx;
            }
            *(h8*)&mB[(size_t)(c * 64 + tbase) * 2] = hv;
            *(h8*)&mB[MID_LO + (size_t)(c * 64 + tbase) * 2] = lv;
        }
    }
}

// ---------------------------------------------------------------------------
// Proj kernel, MFMA split-f16, rot-on-B, T14 async staging, swizzled LDS.
// ---------------------------------------------------------------------------
__global__ __launch_bounds__(256) void proj_kernel(
    const _Float16* __restrict__ wsp,
    const _Float16* __restrict__ mid,
    float* __restrict__ out, int b0, long long out_floats)
{
    const int blk = blockIdx.x;
    int bl, qtr;
    if ((gridDim.x & 31) == 0) {
        int xcd = blk & 7;
        int slot = blk >> 3;
        qtr = slot & 3;
        bl  = ((slot >> 2) << 3) | xcd;
    } else { bl = blk >> 2; qtr = blk & 3; }
    const int b  = b0 + bl;
    const int t  = threadIdx.x;
    const int ln   = t & 15;
    const int quad = (t >> 4) & 3;
    const int wv   = t >> 6;
    const int lnk  = ln & 7;

    __shared__ alignas(16) _Float16 lds[P_LDS_HALFS];
    const _Float16* mB = mid + (size_t)bl * MID_BATCH;

    f4 accR[4], accI[4];
#pragma unroll
    for (int m = 0; m < 4; m++) {
        accR[m] = (f4){0.f, 0.f, 0.f, 0.f};
        accI[m] = (f4){0.f, 0.f, 0.f, 0.f};
    }

    // hoisted staging coordinates (with swizzled LDS offsets)
    int prow[2], pc4[2], plds[2], ptok[2], pcg[2], pxlds[2];
#pragma unroll
    for (int i = 0; i < 2; i++) {
        int p = t + i * 256;
        prow[i] = p >> 3; pc4[i] = p & 7;
        plds[i] = prow[i] * 64 + ((pc4[i] ^ (prow[i] & 7)) << 3);
        ptok[i] = p & 63; pcg[i] = p >> 6;
        pxlds[i] = ptok[i] * 64 + ((pcg[i] ^ (ptok[i] & 7)) << 3);
    }

    h8 wpre[2][2];
    unsigned int mpreH[2][4], mpreL[2][4];

    auto load_chunk = [&](int ch) {
#pragma unroll
        for (int i = 0; i < 2; i++) {
            int grow = 768 + qtr * 64 + prow[i];
            const _Float16* wp = &wsp[(size_t)grow * 512 + ch * 64 + pc4[i] * 8];
            wpre[i][0] = *(const h8*)wp;
            wpre[i][1] = *(const h8*)(wp + WSPLANE);
        }
#pragma unroll
        for (int i = 0; i < 2; i++) {
            int c = ch * 32 + pcg[i] * 4;
#pragma unroll
            for (int j = 0; j < 4; j++) {
                mpreH[i][j] = *(const unsigned int*)&mB[(size_t)((c + j) * 64 + ptok[i]) * 2];
                mpreL[i][j] = *(const unsigned int*)&mB[MID_LO + (size_t)((c + j) * 64 + ptok[i]) * 2];
            }
        }
    };

    load_chunk(0);

    for (int chunk = 0; chunk < 8; chunk++) {
        __syncthreads();
#pragma unroll
        for (int i = 0; i < 2; i++) {
            *(h8*)&lds[PWAH_O + plds[i]] = wpre[i][0];
            *(h8*)&lds[PWAL_O + plds[i]] = wpre[i][1];
        }
#pragma unroll
        for (int i = 0; i < 2; i++) {
            union { h8 v; unsigned int w[4]; } hu, lu;
#pragma unroll
            for (int j = 0; j < 4; j++) { hu.w[j] = mpreH[i][j]; lu.w[j] = mpreL[i][j]; }
            *(h8*)&lds[PXCH_O + pxlds[i]] = hu.v;
            *(h8*)&lds[PXCL_O + pxlds[i]] = lu.v;
        }
        __syncthreads();
        if (chunk < 7) load_chunk(chunk + 1);

#pragma unroll
        for (int ks = 0; ks < 2; ks++) {
            int fblk = ((ks * 4 + quad) ^ lnk) << 3;
            h8 bxh = *(const h8*)&lds[PXCH_O + (wv * 16 + ln) * 64 + fblk];
            h8 bxl = *(const h8*)&lds[PXCL_O + (wv * 16 + ln) * 64 + fblk];
            h8 rxh = rot_neg_hi(bxh);
            h8 rxl = rot_neg_hi(bxl);
#pragma unroll
            for (int mt = 0; mt < 4; mt++) {
                h8 wah = *(const h8*)&lds[PWAH_O + (mt * 16 + ln) * 64 + fblk];
                h8 wal = *(const h8*)&lds[PWAL_O + (mt * 16 + ln) * 64 + fblk];
                accR[mt] = MFMA16(wah, bxh, accR[mt]);
                accR[mt] = MFMA16(wah, bxl, accR[mt]);
                accR[mt] = MFMA16(wal, bxh, accR[mt]);
                accI[mt] = MFMA16(wah, rxh, accI[mt]);
                accI[mt] = MFMA16(wah, rxl, accI[mt]);
                accI[mt] = MFMA16(wal, rxh, accI[mt]);
            }
        }
    }

    // epilogue: planar f32 out
#pragma unroll
    for (int mt = 0; mt < 4; mt++) {
#pragma unroll
        for (int r = 0; r < 4; r++) {
            int o = qtr * 64 + mt * 16 + quad * 4 + r;
            long long idx = ((long long)(b * 256 + o)) * 64 + wv * 16 + ln;
            if (idx < out_floats)
                out[idx] = accR[mt][r];
            if (PLANE + idx < out_floats)
                out[PLANE + idx] = accI[mt][r];
        }
    }
}

extern "C" void kernel_launch(void* const* d_in, const int* in_sizes, int n_in,
                              void* d_out, int out_size, void* d_ws, size_t ws_size,
                              hipStream_t stream) {
    const float* xr  = (const float*)d_in[0];
    const float* xi  = (const float*)d_in[1];
    const float* wqr = (const float*)d_in[2];
    const float* wqi = (const float*)d_in[3];
    const float* wpr = (const float*)d_in[4];
    const float* wpi = (const float*)d_in[5];
    const float* bt  = (const float*)d_in[6];
    const int*   ri  = (const int*)d_in[7];

    const size_t bytes_per_batch = (size_t)MID_BATCH * sizeof(_Float16); // 128 KiB
    const size_t head_bytes = (size_t)WSPLIT_BYTES + BIAS_BYTES;
    if (ws_size < head_bytes + bytes_per_batch) return;

    _Float16* wsp  = (_Float16*)d_ws;
    float*    bsf  = (float*)((char*)d_ws + WSPLIT_BYTES);
    _Float16* mid  = (_Float16*)((char*)d_ws + head_bytes);

    wsplit_kernel<<<256, 256, 0, stream>>>(wqr, wqi, wpr, wpi, wsp);
    bias_kernel<<<128, 256, 0, stream>>>(bt, ri, bsf);

    size_t chunk_sz = (ws_size - head_bytes) / bytes_per_batch;
    if (chunk_sz > BATCH) chunk_sz = BATCH;
    int chunk = (int)chunk_sz;

    for (int b0 = 0; b0 < BATCH; b0 += chunk) {
        int nb = BATCH - b0;
        if (nb > chunk) nb = chunk;
        attn_kernel<<<nb * NHEADS, 256, 0, stream>>>(xr, xi, wsp, bsf, mid, b0);
        proj_kernel<<<nb * 4, 256, 0, stream>>>(wsp, mid, (float*)d_out,
                                                b0, (long long)out_size);
    }
}

// Round 4
// 491.154 us; speedup vs baseline: 3.6740x; 1.1555x over previous
//
#include <hip/hip_runtime.h>
#include <math.h>

#define BATCH 1024
#define CDIM 256
#define NHEADS 8
#define NTOK 64
#define SCALE 0.17677669529663687f  // 32^-0.5

typedef _Float16 h8 __attribute__((ext_vector_type(8)));
typedef _Float16 h2 __attribute__((ext_vector_type(2)));
typedef float f4 __attribute__((ext_vector_type(4)));

#define MFMA16(a, b, c) __builtin_amdgcn_mfma_f32_16x16x32_f16((a), (b), (c), 0, 0, 0)

// ---- workspace layout ----
#define WSPLANE 524288                 // halves per W plane = 1024 * 512
#define WSPLIT_BYTES (2u * WSPLANE * 2u)       // 2 MiB
#define BIAS_FLOATS 32768              // [8][64][64]
#define BIAS_BYTES (BIAS_FLOATS * 4u)  // 128 KiB
#define MID_BATCH 32768                // halves per batch, single f16 plane

// ---- attn LDS plane offsets (halves), stride-64/128 + XOR block swizzle ----
// Phase 1 staging:
#define WAH_O 0        // [96][64] hi of (wr, -wi)
#define WAL_O 6144     // [96][64] lo
#define XCH_O 12288    // [64][64] f16 of (xr, xi)   -> ends 16384
// Phase 2+ aliases the dead staging region (barrier-separated):
#define KAH_O 0        // [64][64] hi of (kr, ki)
#define KAL_O 4096     // [64][64] lo
#define VA_O  8192     // [32][128] (vr, -vi) rows = d, cols = 2*tok
#define PC_O  12288    // [64][128] (pr, pi)  rows = query, cols = 2*key
#define A_LDS_HALFS 20480   // 40960 B -> 4 blocks/CU

// ---- proj LDS (halves) ----
#define PWAH_O 0       // [64][64] hi of (wr, -wi)
#define PWAL_O 4096
#define PXCH_O 8192    // [64][64] f16 of (or, oi)
#define P_LDS_HALFS 12288   // 24576 B -> 6 blocks/CU

#define PLANE 16777216LL

// split v into f16 hi + f16 lo (residual ~2^-22 relative)
__device__ __forceinline__ void fsplit(float v, _Float16& hi, _Float16& lo) {
    _Float16 hh = (_Float16)v;
    hi = hh;
    lo = (_Float16)(v - (float)hh);
}

// per 32b word (a,b) -> (b, -a)
__device__ __forceinline__ h8 rot_neg_hi(h8 a) {
    union { h8 h; unsigned int w[4]; } u; u.h = a;
#pragma unroll
    for (int i = 0; i < 4; i++) {
        unsigned int t = u.w[i];
        t = (t >> 16) | (t << 16);
        u.w[i] = t ^ 0x80000000u;
    }
    return u.h;
}

// ---------------------------------------------------------------------------
// One-time W pre-split: rows 0..767 = w_qkv, rows 768..1023 = w_proj.
// ---------------------------------------------------------------------------
__global__ __launch_bounds__(256) void wsplit_kernel(
    const float* __restrict__ wqr, const float* __restrict__ wqi,
    const float* __restrict__ wpr, const float* __restrict__ wpi,
    _Float16* __restrict__ wsp)
{
    int g = blockIdx.x * 256 + threadIdx.x;   // 0..65535
    int row = g >> 6;                          // 0..1023 (wave-uniform)
    int c = (g & 63) * 4;
    const float* wrp; const float* wip; int srow;
    if (row < 768) { wrp = wqr; wip = wqi; srow = row; }
    else           { wrp = wpr; wip = wpi; srow = row - 768; }
    float4 r4 = *(const float4*)&wrp[srow * 256 + c];
    float4 i4 = *(const float4*)&wip[srow * 256 + c];
    const float* rp = &r4.x;
    const float* ip = &i4.x;
    h8 hi, lo;
#pragma unroll
    for (int j = 0; j < 4; j++) {
        _Float16 h0, l0, h1, l1;
        fsplit(rp[j], h0, l0);
        fsplit(-ip[j], h1, l1);
        hi[2 * j] = h0; hi[2 * j + 1] = h1;
        lo[2 * j] = l0; lo[2 * j + 1] = l1;
    }
    *(h8*)&wsp[(size_t)row * 512 + 2 * c] = hi;
    *(h8*)&wsp[WSPLANE + (size_t)row * 512 + 2 * c] = lo;
}

// ---------------------------------------------------------------------------
// One-time bias expansion: bias_full[h][qrow][mcol] = bt[ri[qrow*64+mcol]*8+h]
// ---------------------------------------------------------------------------
__global__ __launch_bounds__(256) void bias_kernel(
    const float* __restrict__ bt, const int* __restrict__ ri,
    float* __restrict__ bias_full)
{
    int g = blockIdx.x * 256 + threadIdx.x;   // 0..32767
    int hh = g >> 12;
    int pos = g & 4095;
    bias_full[g] = bt[ri[pos] * 8 + hh];
}

// ---------------------------------------------------------------------------
// MFMA attention kernel: one block per (local-batch, head), 256 thr = 4 waves.
// W split-f16 (2^-22), X single f16 (error ~3e-4 rel on q/k/v — below the
// existing f16 P/V error). Q/K in phase 3 remain split from the f32 acc.
// ---------------------------------------------------------------------------
__global__ __launch_bounds__(256) void attn_kernel(
    const float* __restrict__ xr, const float* __restrict__ xi,
    const _Float16* __restrict__ wsp,
    const float* __restrict__ bias_full,
    _Float16* __restrict__ mid, int b0)
{
    const int blk = blockIdx.x;
    // XCD swizzle: all 8 head-blocks of a batch on the same XCD (blk%8).
    int bl, h;
    if ((gridDim.x & 63) == 0) {
        int xcd = blk & 7;
        int slot = blk >> 3;
        h  = slot & 7;
        bl = ((slot >> 3) << 3) | xcd;
    } else { bl = blk >> 3; h = blk & 7; }
    const int b  = b0 + bl;
    const int t  = threadIdx.x;
    const int ln   = t & 15;         // frag 16-index
    const int quad = (t >> 4) & 3;   // frag k-quad
    const int wv   = t >> 6;         // wave id = token-group
    const int lnk  = ln & 7;         // swizzle key for fragment reads

    __shared__ alignas(16) _Float16 lds[A_LDS_HALFS];

    // ---- Phase 1: QKV projection. acc tiles: mt 0,1=q 2,3=k 4,5=v
    f4 accR[6], accI[6];
#pragma unroll
    for (int m = 0; m < 6; m++) {
        accR[m] = (f4){0.f, 0.f, 0.f, 0.f};
        accI[m] = (f4){0.f, 0.f, 0.f, 0.f};
    }

    // hoisted staging coordinates (with swizzled LDS offsets)
    int wlds[3], wgrow[3], wc4[3];
#pragma unroll
    for (int i = 0; i < 3; i++) {
        int p = t + i * 256;
        int row = p >> 3, c4 = p & 7;
        wgrow[i] = (row < 32) ? (h * 32 + row)
                 : (row < 64) ? (256 + h * 32 + (row - 32))
                              : (512 + h * 32 + (row - 64));
        wlds[i] = row * 64 + ((c4 ^ (row & 7)) << 3);
        wc4[i] = c4;
    }
    int xtok[2], xc4g[2], xlds[2];
#pragma unroll
    for (int i = 0; i < 2; i++) {
        int p = t + i * 256;
        xtok[i] = p & 63; xc4g[i] = p >> 6;
        xlds[i] = xtok[i] * 64 + ((xc4g[i] ^ (xtok[i] & 7)) << 3);
    }

    h8 wpre[3][2];
    float xpreR[2][4], xpreI[2][4];

    auto load_chunk = [&](int ch) {
#pragma unroll
        for (int i = 0; i < 3; i++) {
            const _Float16* wp = &wsp[(size_t)wgrow[i] * 512 + ch * 64 + wc4[i] * 8];
            wpre[i][0] = *(const h8*)wp;
            wpre[i][1] = *(const h8*)(wp + WSPLANE);
        }
#pragma unroll
        for (int i = 0; i < 2; i++) {
            int c = ch * 32 + xc4g[i] * 4;
#pragma unroll
            for (int j = 0; j < 4; j++) {
                xpreR[i][j] = xr[(b * 256 + c + j) * 64 + xtok[i]];
                xpreI[i][j] = xi[(b * 256 + c + j) * 64 + xtok[i]];
            }
        }
    };

    load_chunk(0);

    // bias prefetch (L2-resident table; issue early, consume in phase 3)
    float bpre[4][4];
    {
        const float* bfh = &bias_full[h * 4096];
#pragma unroll
        for (int r = 0; r < 4; r++) {
            int qrow = wv * 16 + quad * 4 + r;
#pragma unroll
            for (int mt = 0; mt < 4; mt++)
                bpre[r][mt] = bfh[qrow * 64 + mt * 16 + ln];
        }
    }

    for (int chunk = 0; chunk < 8; chunk++) {
        __syncthreads();     // previous MFMA done reading LDS
#pragma unroll
        for (int i = 0; i < 3; i++) {
            *(h8*)&lds[WAH_O + wlds[i]] = wpre[i][0];
            *(h8*)&lds[WAL_O + wlds[i]] = wpre[i][1];
        }
#pragma unroll
        for (int i = 0; i < 2; i++) {
            h8 hv;
#pragma unroll
            for (int j = 0; j < 4; j++) {
                hv[2 * j]     = (_Float16)xpreR[i][j];
                hv[2 * j + 1] = (_Float16)xpreI[i][j];
            }
            *(h8*)&lds[XCH_O + xlds[i]] = hv;
        }
        __syncthreads();     // LDS ready
        if (chunk < 7) load_chunk(chunk + 1);  // prefetch hides under MFMA

#pragma unroll
        for (int ks = 0; ks < 2; ks++) {
            int fblk = ((ks * 4 + quad) ^ lnk) << 3;
            h8 bxh = *(const h8*)&lds[XCH_O + (wv * 16 + ln) * 64 + fblk];
            h8 rxh = rot_neg_hi(bxh);   // (xi, -xr)
#pragma unroll
            for (int mt = 0; mt < 6; mt++) {
                h8 wah = *(const h8*)&lds[WAH_O + (mt * 16 + ln) * 64 + fblk];
                h8 wal = *(const h8*)&lds[WAL_O + (mt * 16 + ln) * 64 + fblk];
                accR[mt] = MFMA16(wah, bxh, accR[mt]);
                accR[mt] = MFMA16(wal, bxh, accR[mt]);
                accI[mt] = MFMA16(wah, rxh, accI[mt]);
                accI[mt] = MFMA16(wal, rxh, accI[mt]);
            }
        }
    }
    __syncthreads();

    // ---- Phase 2: scatter k (split hi/lo) and v (single f16) to LDS.
    {
        const int tok = wv * 16 + ln;
#pragma unroll
        for (int mt = 2; mt < 4; mt++) {
            int cblk = ((mt - 2) * 4 + quad) ^ (tok & 7);
            h8 hi, lo;
#pragma unroll
            for (int r = 0; r < 4; r++) {
                _Float16 h0, l0, h1, l1;
                fsplit(accR[mt][r], h0, l0);
                fsplit(accI[mt][r], h1, l1);
                hi[2 * r] = h0; hi[2 * r + 1] = h1;
                lo[2 * r] = l0; lo[2 * r + 1] = l1;
            }
            *(h8*)&lds[KAH_O + tok * 64 + (cblk << 3)] = hi;
            *(h8*)&lds[KAL_O + tok * 64 + (cblk << 3)] = lo;
        }
#pragma unroll
        for (int mt = 4; mt < 6; mt++) {
#pragma unroll
            for (int r = 0; r < 4; r++) {
                int d = (mt - 4) * 16 + quad * 4 + r;
                int vblk = (tok >> 2) ^ (d & 7);
                h2 va = {(_Float16)accR[mt][r], (_Float16)(-accI[mt][r])};
                *(h2*)&lds[VA_O + d * 128 + (vblk << 3) + 2 * (tok & 3)] = va;
            }
        }
    }
    __syncthreads();

    // ---- Phase 3: S = scale*(Q conj(K)^H) + bias; magnitude softmax; P -> LDS
    {
        f4 sR[4], sI[4];
#pragma unroll
        for (int m = 0; m < 4; m++) {
            sR[m] = (f4){0.f, 0.f, 0.f, 0.f};
            sI[m] = (f4){0.f, 0.f, 0.f, 0.f};
        }
#pragma unroll
        for (int ks = 0; ks < 2; ks++) {
            // Q fragment built in-register from phase-1 acc (mt = ks)
            h8 qh, ql;
#pragma unroll
            for (int r = 0; r < 4; r++) {
                _Float16 h0, l0, h1, l1;
                fsplit(accR[ks][r], h0, l0);
                fsplit(accI[ks][r], h1, l1);
                qh[2 * r] = h0; qh[2 * r + 1] = h1;
                ql[2 * r] = l0; ql[2 * r + 1] = l1;
            }
            h8 qbh = rot_neg_hi(qh);   // (qi, -qr)
            h8 qbl = rot_neg_hi(ql);
            int fblk = ((ks * 4 + quad) ^ lnk) << 3;
#pragma unroll
            for (int mt = 0; mt < 4; mt++) {
                h8 kh = *(const h8*)&lds[KAH_O + (mt * 16 + ln) * 64 + fblk];
                h8 kl = *(const h8*)&lds[KAL_O + (mt * 16 + ln) * 64 + fblk];
                sR[mt] = MFMA16(qh, kh, sR[mt]);
                sR[mt] = MFMA16(qh, kl, sR[mt]);
                sR[mt] = MFMA16(ql, kh, sR[mt]);
                sI[mt] = MFMA16(qbh, kh, sI[mt]);
                sI[mt] = MFMA16(qbh, kl, sI[mt]);
                sI[mt] = MFMA16(qbl, kh, sI[mt]);
            }
        }
#pragma unroll
        for (int r = 0; r < 4; r++) {
            int qrow = wv * 16 + quad * 4 + r;
            float pr[4], pi[4], mg[4], e[4];
            float mx = -1e30f;
#pragma unroll
            for (int mt = 0; mt < 4; mt++) {
                float bias = bpre[r][mt];
                float srv = sR[mt][r] * SCALE + bias;
                float siv = sI[mt][r] * SCALE;
                pr[mt] = srv; pi[mt] = siv;
                mg[mt] = __builtin_amdgcn_sqrtf(srv * srv + siv * siv);
                mx = fmaxf(mx, mg[mt]);
            }
            mx = fmaxf(mx, __shfl_xor(mx, 1));
            mx = fmaxf(mx, __shfl_xor(mx, 2));
            mx = fmaxf(mx, __shfl_xor(mx, 4));
            mx = fmaxf(mx, __shfl_xor(mx, 8));
            float se = 0.f;
#pragma unroll
            for (int mt = 0; mt < 4; mt++) { e[mt] = __expf(mg[mt] - mx); se += e[mt]; }
            se += __shfl_xor(se, 1);
            se += __shfl_xor(se, 2);
            se += __shfl_xor(se, 4);
            se += __shfl_xor(se, 8);
            float inv = __builtin_amdgcn_rcpf(se);
            int qk = qrow & 7;
#pragma unroll
            for (int mt = 0; mt < 4; mt++) {
                float f = e[mt] * inv * __builtin_amdgcn_rcpf(mg[mt] + 1e-8f);
                h2 p = {(_Float16)(pr[mt] * f), (_Float16)(pi[mt] * f)};
                int pblk = (mt * 4 + (ln >> 2)) ^ qk;
                *(h2*)&lds[PC_O + qrow * 128 + (pblk << 3) + 2 * (ln & 3)] = p;
            }
        }
    }
    __syncthreads();

    // ---- Phase 4: O = P V (complex); store mid as single f16 plane
    {
        f4 oR[2], oI[2];
#pragma unroll
        for (int m = 0; m < 2; m++) {
            oR[m] = (f4){0.f, 0.f, 0.f, 0.f};
            oI[m] = (f4){0.f, 0.f, 0.f, 0.f};
        }
#pragma unroll
        for (int ks = 0; ks < 4; ks++) {
            int fblk = ((ks * 4 + quad) ^ lnk) << 3;
            h8 ap = *(const h8*)&lds[PC_O + (wv * 16 + ln) * 128 + fblk];
            h8 apn = rot_neg_hi(ap);   // (pi, -pr)
#pragma unroll
            for (int dt = 0; dt < 2; dt++) {
                h8 va = *(const h8*)&lds[VA_O + (dt * 16 + ln) * 128 + fblk];
                oR[dt] = MFMA16(ap, va, oR[dt]);
                oI[dt] = MFMA16(apn, va, oI[dt]);
            }
        }
        _Float16* mB = mid + (size_t)bl * MID_BATCH;
#pragma unroll
        for (int dt = 0; dt < 2; dt++) {
            int c = h * 32 + dt * 16 + ln;
            int tbase = wv * 16 + quad * 4;
            h8 hv;
#pragma unroll
            for (int r = 0; r < 4; r++) {
                hv[2 * r]     = (_Float16)oR[dt][r];
                hv[2 * r + 1] = (_Float16)oI[dt][r];
            }
            *(h8*)&mB[(size_t)(c * 64 + tbase) * 2] = hv;
        }
    }
}

// ---------------------------------------------------------------------------
// Proj kernel, MFMA: W_proj split-f16, mid single f16 (error ~2e-5 on out).
// ---------------------------------------------------------------------------
__global__ __launch_bounds__(256) void proj_kernel(
    const _Float16* __restrict__ wsp,
    const _Float16* __restrict__ mid,
    float* __restrict__ out, int b0, long long out_floats)
{
    const int blk = blockIdx.x;
    int bl, qtr;
    if ((gridDim.x & 31) == 0) {
        int xcd = blk & 7;
        int slot = blk >> 3;
        qtr = slot & 3;
        bl  = ((slot >> 2) << 3) | xcd;
    } else { bl = blk >> 2; qtr = blk & 3; }
    const int b  = b0 + bl;
    const int t  = threadIdx.x;
    const int ln   = t & 15;
    const int quad = (t >> 4) & 3;
    const int wv   = t >> 6;
    const int lnk  = ln & 7;

    __shared__ alignas(16) _Float16 lds[P_LDS_HALFS];
    const _Float16* mB = mid + (size_t)bl * MID_BATCH;

    f4 accR[4], accI[4];
#pragma unroll
    for (int m = 0; m < 4; m++) {
        accR[m] = (f4){0.f, 0.f, 0.f, 0.f};
        accI[m] = (f4){0.f, 0.f, 0.f, 0.f};
    }

    // hoisted staging coordinates (with swizzled LDS offsets)
    int prow[2], pc4[2], plds[2], ptok[2], pcg[2], pxlds[2];
#pragma unroll
    for (int i = 0; i < 2; i++) {
        int p = t + i * 256;
        prow[i] = p >> 3; pc4[i] = p & 7;
        plds[i] = prow[i] * 64 + ((pc4[i] ^ (prow[i] & 7)) << 3);
        ptok[i] = p & 63; pcg[i] = p >> 6;
        pxlds[i] = ptok[i] * 64 + ((pcg[i] ^ (ptok[i] & 7)) << 3);
    }

    h8 wpre[2][2];
    unsigned int mpreH[2][4];

    auto load_chunk = [&](int ch) {
#pragma unroll
        for (int i = 0; i < 2; i++) {
            int grow = 768 + qtr * 64 + prow[i];
            const _Float16* wp = &wsp[(size_t)grow * 512 + ch * 64 + pc4[i] * 8];
            wpre[i][0] = *(const h8*)wp;
            wpre[i][1] = *(const h8*)(wp + WSPLANE);
        }
#pragma unroll
        for (int i = 0; i < 2; i++) {
            int c = ch * 32 + pcg[i] * 4;
#pragma unroll
            for (int j = 0; j < 4; j++)
                mpreH[i][j] = *(const unsigned int*)&mB[(size_t)((c + j) * 64 + ptok[i]) * 2];
        }
    };

    load_chunk(0);

    for (int chunk = 0; chunk < 8; chunk++) {
        __syncthreads();
#pragma unroll
        for (int i = 0; i < 2; i++) {
            *(h8*)&lds[PWAH_O + plds[i]] = wpre[i][0];
            *(h8*)&lds[PWAL_O + plds[i]] = wpre[i][1];
        }
#pragma unroll
        for (int i = 0; i < 2; i++) {
            union { h8 v; unsigned int w[4]; } hu;
#pragma unroll
            for (int j = 0; j < 4; j++) hu.w[j] = mpreH[i][j];
            *(h8*)&lds[PXCH_O + pxlds[i]] = hu.v;
        }
        __syncthreads();
        if (chunk < 7) load_chunk(chunk + 1);

#pragma unroll
        for (int ks = 0; ks < 2; ks++) {
            int fblk = ((ks * 4 + quad) ^ lnk) << 3;
            h8 bxh = *(const h8*)&lds[PXCH_O + (wv * 16 + ln) * 64 + fblk];
            h8 rxh = rot_neg_hi(bxh);
#pragma unroll
            for (int mt = 0; mt < 4; mt++) {
                h8 wah = *(const h8*)&lds[PWAH_O + (mt * 16 + ln) * 64 + fblk];
                h8 wal = *(const h8*)&lds[PWAL_O + (mt * 16 + ln) * 64 + fblk];
                accR[mt] = MFMA16(wah, bxh, accR[mt]);
                accR[mt] = MFMA16(wal, bxh, accR[mt]);
                accI[mt] = MFMA16(wah, rxh, accI[mt]);
                accI[mt] = MFMA16(wal, rxh, accI[mt]);
            }
        }
    }

    // epilogue: planar f32 out
#pragma unroll
    for (int mt = 0; mt < 4; mt++) {
#pragma unroll
        for (int r = 0; r < 4; r++) {
            int o = qtr * 64 + mt * 16 + quad * 4 + r;
            long long idx = ((long long)(b * 256 + o)) * 64 + wv * 16 + ln;
            if (idx < out_floats)
                out[idx] = accR[mt][r];
            if (PLANE + idx < out_floats)
                out[PLANE + idx] = accI[mt][r];
        }
    }
}

extern "C" void kernel_launch(void* const* d_in, const int* in_sizes, int n_in,
                              void* d_out, int out_size, void* d_ws, size_t ws_size,
                              hipStream_t stream) {
    const float* xr  = (const float*)d_in[0];
    const float* xi  = (const float*)d_in[1];
    const float* wqr = (const float*)d_in[2];
    const float* wqi = (const float*)d_in[3];
    const float* wpr = (const float*)d_in[4];
    const float* wpi = (const float*)d_in[5];
    const float* bt  = (const float*)d_in[6];
    const int*   ri  = (const int*)d_in[7];

    const size_t bytes_per_batch = (size_t)MID_BATCH * sizeof(_Float16); // 64 KiB
    const size_t head_bytes = (size_t)WSPLIT_BYTES + BIAS_BYTES;
    if (ws_size < head_bytes + bytes_per_batch) return;

    _Float16* wsp  = (_Float16*)d_ws;
    float*    bsf  = (float*)((char*)d_ws + WSPLIT_BYTES);
    _Float16* mid  = (_Float16*)((char*)d_ws + head_bytes);

    wsplit_kernel<<<256, 256, 0, stream>>>(wqr, wqi, wpr, wpi, wsp);
    bias_kernel<<<128, 256, 0, stream>>>(bt, ri, bsf);

    size_t chunk_sz = (ws_size - head_bytes) / bytes_per_batch;
    if (chunk_sz > BATCH) chunk_sz = BATCH;
    int chunk = (int)chunk_sz;

    for (int b0 = 0; b0 < BATCH; b0 += chunk) {
        int nb = BATCH - b0;
        if (nb > chunk) nb = chunk;
        attn_kernel<<<nb * NHEADS, 256, 0, stream>>>(xr, xi, wsp, bsf, mid, b0);
        proj_kernel<<<nb * 4, 256, 0, stream>>>(wsp, mid, (float*)d_out,
                                                b0, (long long)out_size);
    }
}